// Round 17
// baseline (108.344 us; speedup 1.0000x reference)
//
#include <hip/hip_runtime.h>

// NCC loss (B=2, C=1, 160^3 f32, 9^3 box window).
// pass_z      : products + 4-wide sliding z-window (R5-proven config)
//               -> fp8 bufA, layout [b][z][f][y][x] (slice-contiguous).
// pass_yx_mfma: per (b,z,x-tile 16): y- and x-windows as banded-ones MFMA
//               GEMMs: D_f = Band(160x160,|dy|<=4) * S_f * Band^T, with
//               Band generated in-register and K banded (one 16x16x32 bf16
//               MFMA per tile per GEMM). cc element-wise on fragments +
//               deterministic reduction (layout-agnostic).
// finalize    : deterministic reduce.

typedef float floatx2 __attribute__((ext_vector_type(2)));
typedef __attribute__((ext_vector_type(8))) short bf16x8;
typedef __attribute__((ext_vector_type(4))) float f32x4;

constexpr int W = 160, H = 160, D = 160;
constexpr int SLICE = W * H;
constexpr int NVOX  = W * H * D;
constexpr int BATCH = 2;
constexpr float RW  = 1.0f / 729.0f;

// pass_z geometry (R5-proven)
constexpr int TPB_Z = 256;
constexpr int XGZ   = W / 4;                     // 40
constexpr int CHZ   = 5, NCHZ = D / CHZ;         // 32 z-chunks
constexpr int NTH_Z = BATCH * XGZ * H * NCHZ;    // 409,600
constexpr int NBLK_Z = NTH_Z / TPB_Z;            // 1600

// pass_yx_mfma geometry
constexpr int TPB_M = 320;                       // 5 waves
constexpr int NXS   = 10;                        // x'-tiles of 16
constexpr int NBLK_M = BATCH * D * NXS;          // 3200
constexpr int STP   = 184;                       // ST row pad (bf16, 368 B, 16-mult)
constexpr int BBP   = 40;                        // Bb row pad (bf16, 80 B, 16-mult)

// ---- fp8 / bf16 helpers --------------------------------------------------
__device__ inline unsigned int pk4(float a, float b, float c, float d) {
    unsigned int u = 0;
    u = __builtin_amdgcn_cvt_pk_fp8_f32(a, b, u, false);
    u = __builtin_amdgcn_cvt_pk_fp8_f32(c, d, u, true);
    return u;
}
__device__ inline void up4(unsigned int v, float* o) {
    floatx2 t;
    t = __builtin_amdgcn_cvt_pk_f32_fp8(v, false); o[0] = t[0]; o[1] = t[1];
    t = __builtin_amdgcn_cvt_pk_f32_fp8(v, true);  o[2] = t[0]; o[3] = t[1];
}
__device__ inline unsigned short f2bf(float f) {
    unsigned int u = __builtin_bit_cast(unsigned int, f);
    u += 0x7fffu + ((u >> 16) & 1u);
    return (unsigned short)(u >> 16);
}

// ---- pass 1: products + sliding z-window (R5 body, slice layout) ---------
__global__ __launch_bounds__(TPB_Z) void pass_z(const float* __restrict__ I,
                                                const float* __restrict__ J,
                                                unsigned char* __restrict__ outA) {
    int t = blockIdx.x * TPB_Z + threadIdx.x;
    int xg = t % XGZ;
    int y  = (t / XGZ) % H;
    int c  = (t / (XGZ * H)) % NCHZ;
    int b  = t / (XGZ * H * NCHZ);
    int x0 = xg * 4;
    const float* Ib = I + (size_t)b * NVOX + y * W + x0;
    const float* Jb = J + (size_t)b * NVOX + y * W + x0;

    float s[5][4];
#pragma unroll
    for (int f = 0; f < 5; ++f)
#pragma unroll
        for (int i = 0; i < 4; ++i) s[f][i] = 0.f;

    auto addS = [&](int zz) {
        float4 a = *(const float4*)(Ib + (size_t)zz * SLICE);
        float4 bb = *(const float4*)(Jb + (size_t)zz * SLICE);
        float av[4] = {a.x, a.y, a.z, a.w};
        float bv[4] = {bb.x, bb.y, bb.z, bb.w};
#pragma unroll
        for (int i = 0; i < 4; ++i) {
            float x = av[i], yv = bv[i];
            s[0][i] += x; s[1][i] += yv;
            s[2][i] += x * x; s[3][i] += yv * yv; s[4][i] += x * yv;
        }
    };
    auto subS = [&](int zz) {
        float4 a = *(const float4*)(Ib + (size_t)zz * SLICE);
        float4 bb = *(const float4*)(Jb + (size_t)zz * SLICE);
        float av[4] = {a.x, a.y, a.z, a.w};
        float bv[4] = {bb.x, bb.y, bb.z, bb.w};
#pragma unroll
        for (int i = 0; i < 4; ++i) {
            float x = av[i], yv = bv[i];
            s[0][i] -= x; s[1][i] -= yv;
            s[2][i] -= x * x; s[3][i] -= yv * yv; s[4][i] -= x * yv;
        }
    };

    int z0 = c * CHZ;
    for (int zz = (z0 - 4 < 0 ? 0 : z0 - 4); zz <= z0 + 4; ++zz) addS(zz);

    for (int dz = 0; dz < CHZ; ++dz) {
        int z = z0 + dz;
        unsigned char* op = outA + ((size_t)(b * D + z) * 5) * SLICE + y * W + x0;
#pragma unroll
        for (int f = 0; f < 5; ++f)
            *(unsigned int*)(op + (size_t)f * SLICE) = pk4(s[f][0], s[f][1], s[f][2], s[f][3]);
        int za = z + 5; if (za < D) addS(za);
        int zs = z - 4; if (zs >= 0) subS(zs);
    }
}

// ---- pass 2: banded-MFMA y+x windows + cc + reduce -----------------------
__global__ __launch_bounds__(TPB_M) void pass_yx_mfma(const unsigned char* __restrict__ A,
                                                      double* __restrict__ partials) {
    __shared__ unsigned short ST[32][STP];   // S^T strip, bf16: x-local rows, y+8 cols
    __shared__ unsigned short Bb[160][BBP];  // C1 [m][n_loc] bf16
    __shared__ double sm[TPB_M / 64];

    int blk = blockIdx.x;
    int xs = blk % NXS;
    int z  = (blk / NXS) % D;
    int b  = blk / (NXS * D);
    int x0 = xs * 16;
    int tid = threadIdx.x;
    int lane = tid & 63, wv = tid >> 6;      // 5 waves

    // zero ST y-pads (cols [0,8) and [168,STP)) once
    for (int i = tid; i < 32 * STP; i += TPB_M) {
        int col = i % STP;
        if (col < 8 || col >= 168) ST[i / STP][col] = 0;
    }

    // constant band fragment: A[m][k], bf16 1.0 iff |k-m|<=4
    // lane: m_loc = lane&15, k_loc = (lane>>4)*8 + j; Delta = -8 + k_loc - m_loc
    bf16x8 band;
    {
        int dbase = -8 + ((lane >> 4) << 3) - (lane & 15);
#pragma unroll
        for (int j = 0; j < 8; ++j) {
            int d = dbase + j;
            band[j] = (short)((d >= -4 && d <= 4) ? 0x3F80 : 0);
        }
    }

    float d2s[5][2][4];

#pragma unroll
    for (int f = 0; f < 5; ++f) {
        // ---- stage S^T strip (fp8 -> bf16), rows = x-local [0,32) -------
        {
            int y = tid % 160, xh = tid / 160;           // xh 0/1
            int xstart = x0 - 8 + xh * 16;
            const unsigned char* src = A + ((size_t)(b * D + z) * 5 + f) * SLICE + (size_t)y * W;
            unsigned int cs[4];
            if (xstart >= 0 && xstart + 16 <= W) {
                uint4 v = *(const uint4*)(src + xstart);
                cs[0] = v.x; cs[1] = v.y; cs[2] = v.z; cs[3] = v.w;
            } else {
#pragma unroll
                for (int q = 0; q < 4; ++q) {
                    unsigned int v = 0;
#pragma unroll
                    for (int i = 0; i < 4; ++i) {
                        int xx = xstart + q * 4 + i;
                        unsigned int bb = (xx >= 0 && xx < W) ? (unsigned int)src[xx] : 0u;
                        v |= bb << (8 * i);
                    }
                    cs[q] = v;
                }
            }
#pragma unroll
            for (int q = 0; q < 4; ++q) {
                float u[4]; up4(cs[q], u);
#pragma unroll
                for (int i = 0; i < 4; ++i)
                    ST[xh * 16 + q * 4 + i][y + 8] = f2bf(u[i]);
            }
        }
        __syncthreads();

        // ---- GEMM1: C1[m][n_loc] = Band * S  (wave owns m-tiles 2wv,2wv+1)
        f32x4 c1[2][2];
#pragma unroll
        for (int mt = 0; mt < 2; ++mt) {
            int m0 = (wv * 2 + mt) * 16;
#pragma unroll
            for (int nt = 0; nt < 2; ++nt) {
                // B-frag: n_loc = nt*16 + (lane&15); k col = m0 + (lane>>4)*8 (+8 offset)
                const unsigned short* p = &ST[nt * 16 + (lane & 15)][m0 + ((lane >> 4) << 3)];
                bf16x8 bfrag = *(const bf16x8*)p;
                f32x4 zz = {0.f, 0.f, 0.f, 0.f};
                c1[mt][nt] = __builtin_amdgcn_mfma_f32_16x16x32_bf16(band, bfrag, zz, 0, 0, 0);
            }
            // write C1 frags to Bb[m][n_loc] (bf16); rows owned by this wave
#pragma unroll
            for (int nt = 0; nt < 2; ++nt)
#pragma unroll
                for (int r = 0; r < 4; ++r)
                    Bb[m0 + ((lane >> 4) << 2) + r][nt * 16 + (lane & 15)] = f2bf(c1[mt][nt][r]);
        }

        // ---- GEMM2: D[x'][m] = Band * C1^T-ish (B-frag from Bb rows) ----
#pragma unroll
        for (int mt = 0; mt < 2; ++mt) {
            int m0 = (wv * 2 + mt) * 16;
            const unsigned short* p = &Bb[m0 + (lane & 15)][((lane >> 4) << 3)];
            bf16x8 bfrag = *(const bf16x8*)p;
            f32x4 zz = {0.f, 0.f, 0.f, 0.f};
            f32x4 dd = __builtin_amdgcn_mfma_f32_16x16x32_bf16(band, bfrag, zz, 0, 0, 0);
#pragma unroll
            for (int r = 0; r < 4; ++r) d2s[f][mt][r] = dd[r];
        }
        __syncthreads();   // all waves done with ST/Bb before next field
    }

    // ---- cc on fragments (layout-agnostic) + reduction -------------------
    double acc = 0.0;
#pragma unroll
    for (int mt = 0; mt < 2; ++mt) {
#pragma unroll
        for (int r = 0; r < 4; ++r) {
            float Is = d2s[0][mt][r], Js = d2s[1][mt][r];
            float I2s = d2s[2][mt][r], J2s = d2s[3][mt][r], IJs = d2s[4][mt][r];
            float tI = RW * Is;
            float cross = __builtin_fmaf(-tI, Js, IJs);
            float Iv    = __builtin_fmaf(-tI, Is, I2s);
            float Jv    = __builtin_fmaf(-(RW * Js), Js, J2s);
            float den   = __builtin_fmaf(Iv, Jv, 1e-5f);
            acc += (double)(cross * cross * __builtin_amdgcn_rcpf(den));
        }
    }

#pragma unroll
    for (int off = 32; off > 0; off >>= 1) acc += __shfl_down(acc, off);
    if (lane == 0) sm[wv] = acc;
    __syncthreads();
    if (tid == 0) {
        double tt = 0.0;
#pragma unroll
        for (int i = 0; i < TPB_M / 64; ++i) tt += sm[i];
        partials[blockIdx.x] = tt;
    }
}

// ---- final deterministic reduce ------------------------------------------
__global__ __launch_bounds__(256) void finalize(const double* __restrict__ p,
                                                float* __restrict__ out) {
    double v = 0.0;
    for (int i = threadIdx.x; i < NBLK_M; i += 256) v += p[i];
#pragma unroll
    for (int off = 32; off > 0; off >>= 1) v += __shfl_down(v, off);
    __shared__ double sm[4];
    int lane = threadIdx.x & 63, wid = threadIdx.x >> 6;
    if (lane == 0) sm[wid] = v;
    __syncthreads();
    if (threadIdx.x == 0) {
        double tt = 0.0;
#pragma unroll
        for (int i = 0; i < 4; ++i) tt += sm[i];
        out[0] = (float)(1.0 - tt / (double)((double)BATCH * (double)NVOX));
    }
}

extern "C" void kernel_launch(void* const* d_in, const int* in_sizes, int n_in,
                              void* d_out, int out_size, void* d_ws, size_t ws_size,
                              hipStream_t stream) {
    const float* I = (const float*)d_in[0];
    const float* J = (const float*)d_in[1];
    float* out = (float*)d_out;

    // ws: bufA (41 MB fp8, [b][z][f][y][x]) | partials (NBLK_M f64)
    size_t bufsz = ((size_t)BATCH * 5 * NVOX + 255) / 256 * 256;
    unsigned char* bufA = (unsigned char*)d_ws;
    double* partials = (double*)(bufA + bufsz);

    pass_z<<<NBLK_Z, TPB_Z, 0, stream>>>(I, J, bufA);
    pass_yx_mfma<<<NBLK_M, TPB_M, 0, stream>>>(bufA, partials);
    finalize<<<1, 256, 0, stream>>>(partials, out);
}

// Round 18
// 59.777 us; speedup vs baseline: 1.8125x; 1.8125x over previous
//
#include <hip/hip_runtime.h>

// NCC loss (B=2, C=1, 160^3 f32, 9^3 box window). Two passes + reduce.
// pass_pzx: (R16-proven, 60.2us config) block=(b,y,xt 80,zc 80). Staging:
//           x-windowed products -> fp8 LDS [5][88][80]; one barrier; 400
//           threads slide 9-tap z-windows across 4 z each
//           -> fp8 bufA [b][z][y][f][x] (800 B row-groups).
// pass_y2 : block=(b,z,y-quarter 40). Stage 48 row-groups (38.4 KB) into
//           LDS with coalesced uint4 loads (compulsory bytes only), then
//           20x20 threads slide 9-tap y-windows over LDS rows + cc +
//           deterministic reduction. No scattered global taps.
// finalize: deterministic reduce.

typedef float floatx2 __attribute__((ext_vector_type(2)));

constexpr int W = 160, H = 160, D = 160;
constexpr int SLICE = W * H;
constexpr int NVOX  = W * H * D;
constexpr int BATCH = 2;
constexpr int FROW  = 5 * W;             // 800 B per (b,z,y) row-group
constexpr float RW  = 1.0f / 729.0f;

// pass_pzx geometry (R16-proven)
constexpr int TPB_P = 400;
constexpr int XT    = 80;                // x-tile width
constexpr int NXT   = W / XT;            // 2
constexpr int CZ    = 80;                // z outputs per block
constexpr int NCZ   = D / CZ;            // 2
constexpr int ZS    = CZ + 8;            // 88 staged slices
constexpr int NUNITS = ZS * 10;          // 880 staging units
constexpr int NBLK_P = BATCH * H * NXT * NCZ;    // 1280

// pass_y2 geometry
constexpr int TPB_Y = 448;               // 7 waves
constexpr int YQ    = 40;                // y outputs per block
constexpr int NYQ   = H / YQ;            // 4
constexpr int YR    = YQ + 8;            // 48 staged rows
constexpr int NBLK_Y = BATCH * D * NYQ;  // 1280
constexpr int LDW   = YR * FROW / 16;    // 2400 uint4 stage loads

// ---- fp8 helpers (HW cvt, OCP e4m3) --------------------------------------
__device__ inline unsigned int pk4(float a, float b, float c, float d) {
    unsigned int u = 0;
    u = __builtin_amdgcn_cvt_pk_fp8_f32(a, b, u, false);
    u = __builtin_amdgcn_cvt_pk_fp8_f32(c, d, u, true);
    return u;
}
__device__ inline void up4(unsigned int v, float* o) {
    floatx2 t;
    t = __builtin_amdgcn_cvt_pk_f32_fp8(v, false); o[0] = t[0]; o[1] = t[1];
    t = __builtin_amdgcn_cvt_pk_f32_fp8(v, true);  o[2] = t[0]; o[3] = t[1];
}
__device__ inline void up8(uint2 v, float* o) {
    up4(v.x, o); up4(v.y, o + 4);
}

// ---- pass 1: x-window at staging -> fp8 LDS; 4-z sliding z-window --------
__global__ __launch_bounds__(TPB_P) void pass_pzx(const float* __restrict__ I,
                                                  const float* __restrict__ J,
                                                  unsigned char* __restrict__ outA) {
    __shared__ unsigned char xw[5][ZS][XT];    // fp8, 35,200 B

    int blk = blockIdx.x;
    int zc = blk % NCZ;
    int xt = (blk / NCZ) % NXT;
    int y  = (blk / (NCZ * NXT)) % H;
    int b  = blk / (NCZ * NXT * H);
    int tx0 = xt * XT;
    int zbase = zc * CZ - 4;
    const float* Ib = I + (size_t)b * NVOX + y * W;
    const float* Jb = J + (size_t)b * NVOX + y * W;

    // ---- staging: 880 (slice, 8-x) units over 400 threads ----------------
    const float4 Z4 = make_float4(0.f, 0.f, 0.f, 0.f);
    for (int u = threadIdx.x; u < NUNITS; u += TPB_P) {
        int zs = u / 10;
        int xu = u % 10;
        int gxs = tx0 + xu * 8;
        int gz = zbase + zs;
        float a[16], c[16];
        if (gz >= 0 && gz < D) {
            const float* ip = Ib + (size_t)gz * SLICE + gxs;
            const float* jp = Jb + (size_t)gz * SLICE + gxs;
            float4 A0 = (gxs >= 4)     ? *(const float4*)(ip - 4) : Z4;
            float4 A1 = *(const float4*)(ip);
            float4 A2 = *(const float4*)(ip + 4);
            float4 A3 = (gxs + 11 < W) ? *(const float4*)(ip + 8) : Z4;
            float4 C0 = (gxs >= 4)     ? *(const float4*)(jp - 4) : Z4;
            float4 C1 = *(const float4*)(jp);
            float4 C2 = *(const float4*)(jp + 4);
            float4 C3 = (gxs + 11 < W) ? *(const float4*)(jp + 8) : Z4;
            float at[16] = {A0.x,A0.y,A0.z,A0.w, A1.x,A1.y,A1.z,A1.w,
                            A2.x,A2.y,A2.z,A2.w, A3.x,A3.y,A3.z,A3.w};
            float ct[16] = {C0.x,C0.y,C0.z,C0.w, C1.x,C1.y,C1.z,C1.w,
                            C2.x,C2.y,C2.z,C2.w, C3.x,C3.y,C3.z,C3.w};
#pragma unroll
            for (int k = 0; k < 16; ++k) { a[k] = at[k]; c[k] = ct[k]; }
        } else {
#pragma unroll
            for (int k = 0; k < 16; ++k) { a[k] = 0.f; c[k] = 0.f; }
        }
#pragma unroll
        for (int f = 0; f < 5; ++f) {
            float v[16];
#pragma unroll
            for (int k = 0; k < 16; ++k) {
                float x = a[k], yv = c[k];
                v[k] = (f == 0) ? x : (f == 1) ? yv :
                       (f == 2) ? x * x : (f == 3) ? yv * yv : x * yv;
            }
            float P[16];
            P[0] = v[0];
#pragma unroll
            for (int k = 1; k < 16; ++k) P[k] = P[k - 1] + v[k];
            float w[8];
            w[0] = P[8];
#pragma unroll
            for (int j = 1; j < 8; ++j) w[j] = P[j + 8] - P[j - 1];
            uint2 pk;
            pk.x = pk4(w[0], w[1], w[2], w[3]);
            pk.y = pk4(w[4], w[5], w[6], w[7]);
            *(uint2*)&xw[f][zs][xu * 8] = pk;
        }
    }

    __syncthreads();

    // ---- compute: 20 xg (4x) x 20 zl (4z each), sliding 9-tap z-window ---
    {
        int xg = threadIdx.x % 20;
        int zl = threadIdx.x / 20;       // 0..19
        int x0l = xg * 4;
        int zo0 = zl * 4;

        float acc[5][4];
#pragma unroll
        for (int f = 0; f < 5; ++f)
#pragma unroll
            for (int i = 0; i < 4; ++i) acc[f][i] = 0.f;

#pragma unroll
        for (int k = 0; k < 9; ++k) {
#pragma unroll
            for (int f = 0; f < 5; ++f) {
                unsigned int v = *(const unsigned int*)&xw[f][zo0 + k][x0l];
                float u[4]; up4(v, u);
                acc[f][0] += u[0]; acc[f][1] += u[1];
                acc[f][2] += u[2]; acc[f][3] += u[3];
            }
        }

        int gz0 = zc * CZ + zo0;
        unsigned char* op = outA + ((size_t)(b * D + gz0) * H + y) * FROW + tx0 + x0l;
#pragma unroll
        for (int q = 0; q < 4; ++q) {
#pragma unroll
            for (int f = 0; f < 5; ++f)
                *(unsigned int*)(op + f * W) =
                    pk4(acc[f][0], acc[f][1], acc[f][2], acc[f][3]);
            if (q < 3) {
#pragma unroll
                for (int f = 0; f < 5; ++f) {
                    unsigned int ve = *(const unsigned int*)&xw[f][zo0 + 9 + q][x0l];
                    unsigned int vl = *(const unsigned int*)&xw[f][zo0 + q][x0l];
                    float ue[4], ul[4];
                    up4(ve, ue); up4(vl, ul);
                    acc[f][0] += ue[0] - ul[0]; acc[f][1] += ue[1] - ul[1];
                    acc[f][2] += ue[2] - ul[2]; acc[f][3] += ue[3] - ul[3];
                }
                op += (size_t)H * FROW;
            }
        }
    }
}

// ---- pass 2: LDS-staged y-slide + cc + reduce ----------------------------
__global__ __launch_bounds__(TPB_Y) void pass_y2(const unsigned char* __restrict__ A,
                                                 double* __restrict__ partials) {
    __shared__ unsigned char rows[YR * FROW];   // 38,400 B fp8
    __shared__ double sm[TPB_Y / 64];

    int blk = blockIdx.x;
    int yq = blk % NYQ;
    int z  = (blk / NYQ) % D;
    int b  = blk / (NYQ * D);
    int y0 = yq * YQ;
    int tid = threadIdx.x;
    const unsigned char* __restrict__ src =
        A + ((size_t)(b * D + z) * H) * FROW;

    // ---- stage 48 row-groups, coalesced uint4; OOB rows -> zero ----------
    for (int i = tid; i < LDW; i += TPB_Y) {
        int off = i * 16;
        int r = off / FROW;
        int gy = y0 - 4 + r;
        uint4 v = make_uint4(0u, 0u, 0u, 0u);
        if (gy >= 0 && gy < H)
            v = *(const uint4*)(src + (size_t)gy * FROW + (off % FROW));
        *(uint4*)&rows[off] = v;
    }
    __syncthreads();

    // ---- compute: 20 xg x 20 y-strips (2 outputs each), slide over LDS ---
    double acc = 0.0;
    if (tid < 400) {
        int xg = tid % 20;
        int ys = tid / 20;               // 0..19
        int rbase = ys * 2;              // local row of first tap
        int x8 = xg * 8;

        float s[5][8];
#pragma unroll
        for (int f = 0; f < 5; ++f)
#pragma unroll
            for (int i = 0; i < 8; ++i) s[f][i] = 0.f;

        // init 9-tap window: local rows rbase .. rbase+8
#pragma unroll
        for (int t = 0; t < 9; ++t) {
            const unsigned char* rp = &rows[(rbase + t) * FROW + x8];
#pragma unroll
            for (int f = 0; f < 5; ++f) {
                uint2 v = *(const uint2*)(rp + f * W);
                float u[8]; up8(v, u);
#pragma unroll
                for (int i = 0; i < 8; ++i) s[f][i] += u[i];
            }
        }

#pragma unroll
        for (int o = 0; o < 2; ++o) {
            float rowcc = 0.f;
#pragma unroll
            for (int i = 0; i < 8; ++i) {
                float Is = s[0][i], Js = s[1][i];
                float I2s = s[2][i], J2s = s[3][i], IJs = s[4][i];
                float tI = RW * Is;
                float cross = __builtin_fmaf(-tI, Js, IJs);
                float Iv    = __builtin_fmaf(-tI, Is, I2s);
                float Jv    = __builtin_fmaf(-(RW * Js), Js, J2s);
                float den   = __builtin_fmaf(Iv, Jv, 1e-5f);
                rowcc = __builtin_fmaf(cross * cross, __builtin_amdgcn_rcpf(den), rowcc);
            }
            acc += (double)rowcc;
            if (o == 0) {
                // slide one y: add local row rbase+9, subtract rbase
                const unsigned char* re = &rows[(rbase + 9) * FROW + x8];
                const unsigned char* rl = &rows[rbase * FROW + x8];
#pragma unroll
                for (int f = 0; f < 5; ++f) {
                    uint2 ve = *(const uint2*)(re + f * W);
                    uint2 vl = *(const uint2*)(rl + f * W);
                    float ue[8], ul[8];
                    up8(ve, ue); up8(vl, ul);
#pragma unroll
                    for (int i = 0; i < 8; ++i) s[f][i] += ue[i] - ul[i];
                }
            }
        }
    }

    // ---- deterministic block reduction (7 waves; idle lanes acc=0) -------
#pragma unroll
    for (int off = 32; off > 0; off >>= 1) acc += __shfl_down(acc, off);
    if ((tid & 63) == 0) sm[tid >> 6] = acc;
    __syncthreads();
    if (tid == 0) {
        double tt = 0.0;
#pragma unroll
        for (int i = 0; i < TPB_Y / 64; ++i) tt += sm[i];
        partials[blockIdx.x] = tt;
    }
}

// ---- final deterministic reduce ------------------------------------------
__global__ __launch_bounds__(256) void finalize(const double* __restrict__ p,
                                                float* __restrict__ out) {
    double v = 0.0;
    for (int i = threadIdx.x; i < NBLK_Y; i += 256) v += p[i];
#pragma unroll
    for (int off = 32; off > 0; off >>= 1) v += __shfl_down(v, off);
    __shared__ double sm[4];
    int lane = threadIdx.x & 63, wid = threadIdx.x >> 6;
    if (lane == 0) sm[wid] = v;
    __syncthreads();
    if (threadIdx.x == 0) {
        double tt = 0.0;
#pragma unroll
        for (int i = 0; i < 4; ++i) tt += sm[i];
        out[0] = (float)(1.0 - tt / (double)((double)BATCH * (double)NVOX));
    }
}

extern "C" void kernel_launch(void* const* d_in, const int* in_sizes, int n_in,
                              void* d_out, int out_size, void* d_ws, size_t ws_size,
                              hipStream_t stream) {
    const float* I = (const float*)d_in[0];
    const float* J = (const float*)d_in[1];
    float* out = (float*)d_out;

    // ws: bufA (41 MB fp8, [b][z][y][f][x]) | partials (NBLK_Y f64)
    size_t bufsz = ((size_t)BATCH * 5 * NVOX + 255) / 256 * 256;
    unsigned char* bufA = (unsigned char*)d_ws;
    double* partials = (double*)(bufA + bufsz);

    pass_pzx<<<NBLK_P, TPB_P, 0, stream>>>(I, J, bufA);
    pass_y2<<<NBLK_Y, TPB_Y, 0, stream>>>(bufA, partials);
    finalize<<<1, 256, 0, stream>>>(partials, out);
}